// Round 9
// baseline (883.947 us; speedup 1.0000x reference)
//
#include <hip/hip_runtime.h>
#include <stdint.h>

// ---------- bf16 helpers (raw ushort representation, RNE) ----------
__device__ __forceinline__ float b2f(unsigned short s) {
    union { uint32_t u; float f; } v; v.u = ((uint32_t)s) << 16; return v.f;
}
__device__ __forceinline__ unsigned short f2b(float f) {
    union { float f; uint32_t u; } v; v.f = f;
    uint32_t r = v.u + 0x7FFFu + ((v.u >> 16) & 1u);
    return (unsigned short)(r >> 16);
}
__device__ __forceinline__ int ld_idx(const void* p, long long i, int i64) {
    return i64 ? (int)((const long long*)p)[i] : ((const int*)p)[i];
}

typedef __bf16 bf16x8 __attribute__((ext_vector_type(8)));
typedef float  f32x4  __attribute__((ext_vector_type(4)));

// ---------- dtype detection: flags[0]=floats-are-f32, flags[1]=ints-are-i64 ----------
__global__ void detect_kernel(const void* __restrict__ x, const void* __restrict__ eidx,
                              int* __restrict__ flags) {
    __shared__ int cntF, cntI;
    int t = threadIdx.x;
    if (t == 0) { cntF = 0; cntI = 0; }
    __syncthreads();
    const unsigned short* xs = (const unsigned short*)x;
    int lf = 0;
    for (int i = t; i < 4096; i += 256) {
        unsigned short v = xs[2 * i];
        int e = (v >> 7) & 0xFF;
        if (v == 0 || (e >= 100 && e <= 140)) lf++;
    }
    const int* ei = (const int*)eidx;
    int li = 0;
    for (int i = t; i < 2048; i += 256)
        if (ei[2 * i + 1] != 0) li++;
    atomicAdd(&cntF, lf);
    atomicAdd(&cntI, li);
    __syncthreads();
    if (t == 0) {
        flags[0] = (cntF < 3000) ? 1 : 0;
        flags[1] = (cntI < 64) ? 1 : 0;
    }
}

// ---------- transpose + convert: Wt[n*K+k] = bf16(W[src_off + k*N+n]) ----------
__global__ void convt_kernel(const void* __restrict__ W, size_t src_off,
                             unsigned short* __restrict__ Wt, int K, int N,
                             const int* __restrict__ flags) {
    int id = blockIdx.x * 256 + threadIdx.x;
    if (id < K * N) {
        int n = id / K, k = id - n * K;
        size_t s = src_off + (size_t)k * N + n;
        Wt[id] = flags[0] ? f2b(((const float*)W)[s]) : ((const unsigned short*)W)[s];
    }
}

__global__ void convb_kernel(const void* __restrict__ src, unsigned short* __restrict__ dst,
                             int n, const int* __restrict__ flags) {
    int i = blockIdx.x * 256 + threadIdx.x;
    if (i < n)
        dst[i] = flags[0] ? f2b(((const float*)src)[i]) : ((const unsigned short*)src)[i];
}

// ---------- x -> bf16 bulk convert (8 elems/thread) ----------
__global__ void convx_kernel(const void* __restrict__ src, unsigned short* __restrict__ dst,
                             int n8, const int* __restrict__ flags) {
    int i = blockIdx.x * 256 + threadIdx.x;
    if (i < n8) {
        if (flags[0]) {
            const float4* p = (const float4*)src + (size_t)i * 2;
            float4 a = p[0], b = p[1];
            union { int4 v; unsigned short s[8]; } u;
            u.s[0] = f2b(a.x); u.s[1] = f2b(a.y); u.s[2] = f2b(a.z); u.s[3] = f2b(a.w);
            u.s[4] = f2b(b.x); u.s[5] = f2b(b.y); u.s[6] = f2b(b.z); u.s[7] = f2b(b.w);
            ((int4*)dst)[i] = u.v;
        } else {
            ((int4*)dst)[i] = ((const int4*)src)[i];
        }
    }
}

__global__ void zero_kernel(int* __restrict__ p, int n) {
    int i = blockIdx.x * 256 + threadIdx.x;
    if (i < n) p[i] = 0;
}
__global__ void zero_us_kernel(unsigned short* __restrict__ p, int n) {
    int i = blockIdx.x * 256 + threadIdx.x;
    if (i < n) p[i] = 0;
}

// ---------- per-(relation,dst) edge counts (flag-aware, clamped) ----------
__global__ void count_kernel(const void* __restrict__ eidx, const void* __restrict__ etype,
                             int* __restrict__ cnt, int E, int NN,
                             const int* __restrict__ flags) {
    int e = blockIdx.x * 256 + threadIdx.x;
    if (e < E) {
        int i64 = flags[1];
        int d = ld_idx(eidx, (long long)E + e, i64);
        d = min(max(d, 0), NN - 1);
        int ty = ld_idx(etype, e, i64) & 1;
        atomicAdd(&cnt[ty * NN + d], 1);
    }
}

__global__ void inv_deg_kernel(const int* __restrict__ cnt, float* __restrict__ inv,
                               int* __restrict__ deg, int NN) {
    int i = blockIdx.x * 256 + threadIdx.x;
    if (i < NN) {
        int c0 = cnt[i], c1 = cnt[NN + i];
        inv[i]      = 1.0f / (float)max(c0, 1);
        inv[NN + i] = 1.0f / (float)max(c1, 1);
        deg[i] = c0 + c1;
    }
}

// ---------- 3-phase parallel scan (round-7-proven) ----------
__global__ void blocksum_kernel(const int* __restrict__ deg, int* __restrict__ bsum, int n) {
    __shared__ int red[256];
    int t = threadIdx.x, b = blockIdx.x;
    int base = b * 1024 + t * 4;
    int s = 0;
    #pragma unroll
    for (int j = 0; j < 4; ++j) {
        int idx = base + j;
        if (idx < n) s += deg[idx];
    }
    red[t] = s;
    __syncthreads();
    for (int off = 128; off > 0; off >>= 1) {
        if (t < off) red[t] += red[t + off];
        __syncthreads();
    }
    if (t == 0) bsum[b] = red[0];
}
__global__ void scan_bsum_kernel(int* __restrict__ bsum, int nb) {
    if (threadIdx.x == 0 && blockIdx.x == 0) {
        int acc = 0;
        for (int i = 0; i < nb; ++i) { int v = bsum[i]; bsum[i] = acc; acc += v; }
    }
}
__global__ void scan_phase3(const int* __restrict__ deg, const int* __restrict__ bsum,
                            int* __restrict__ row_ptr, int* __restrict__ pos, int n) {
    __shared__ int buf[256];
    int t = threadIdx.x, b = blockIdx.x;
    int base = b * 1024;
    int v[4]; int s = 0;
    #pragma unroll
    for (int j = 0; j < 4; ++j) {
        int idx = base + t * 4 + j;
        v[j] = (idx < n) ? deg[idx] : 0;
        s += v[j];
    }
    buf[t] = s;
    __syncthreads();
    for (int off = 1; off < 256; off <<= 1) {
        int xv = (t >= off) ? buf[t - off] : 0;
        __syncthreads();
        buf[t] += xv;
        __syncthreads();
    }
    int run = buf[t] - s + bsum[b];
    #pragma unroll
    for (int j = 0; j < 4; ++j) {
        int idx = base + t * 4 + j;
        if (idx < n) {
            run += v[j];
            row_ptr[idx + 1] = run;
            if (idx + 1 < n) pos[idx + 1] = run;
        }
    }
    if (b == 0 && t == 0) { row_ptr[0] = 0; pos[0] = 0; }
}

// ---------- CSR fill: packed[slot] = (rel<<24) | src ----------
__global__ void fill_kernel(const void* __restrict__ eidx, const void* __restrict__ etype,
                            int* __restrict__ pos, int* __restrict__ packed, int E, int NN,
                            const int* __restrict__ flags) {
    int e = blockIdx.x * 256 + threadIdx.x;
    if (e < E) {
        int i64 = flags[1];
        int s = ld_idx(eidx, e, i64);
        int d = ld_idx(eidx, (long long)E + e, i64);
        s = min(max(s, 0), NN - 1);
        d = min(max(d, 0), NN - 1);
        int ty = ld_idx(etype, e, i64) & 1;
        int slot = atomicAdd(&pos[d], 1);
        packed[slot] = (ty << 24) | s;
    }
}

// ---------- MFMA bf16 GEMM: C[M,N] = act(A[M,K] @ Wt[N,K]^T + bias) ----------
// Tile 128x128, BK=64, 256 threads = 4 waves (2x2), each wave 64x64 via 4x4 of 16x16x32.
// A: r8-proven guarded int4 register staging into padded As[128][72].
// B: global_load_lds direct-to-LDS (m97 idiom), unpadded Bs[128*64]; B rows always in-bounds.
// grid: x = N/128 fastest (A row-stripe L2 reuse), y = ceil(M/128).
template<bool LEAKY, bool HAS_BIAS>
__global__ __launch_bounds__(256) void gemm_kernel(
    const unsigned short* __restrict__ A,    // [M,K] bf16
    const unsigned short* __restrict__ Wt,   // [N,K] bf16
    const unsigned short* __restrict__ bias, // [N] bf16, or null
    unsigned short* __restrict__ C,          // [M,N] bf16
    int M, int N, int K)
{
    __shared__ __align__(16) unsigned short As[128][72];
    __shared__ __align__(16) unsigned short Bs[128 * 64];

    const int t    = threadIdx.x;
    const int lane = t & 63;
    const int wave = t >> 6;
    const int wm   = wave >> 1;
    const int wn   = wave & 1;
    const int l16  = lane & 15;
    const int quad = lane >> 4;
    const int col0 = blockIdx.x * 128;
    const int row0 = blockIdx.y * 128;
    // B staging coords: wave w, issue j covers Bs rows j*32 + w*8 .. +8 (64 lanes x 16B)
    const int srow = wave * 8 + (lane >> 3);
    const int scol = (lane & 7) * 8;

    f32x4 acc[4][4] = {};

    for (int k0 = 0; k0 < K; k0 += 64) {
        // ---- B tile via global_load_lds (wave-uniform LDS base + lane*16B) ----
        #pragma unroll
        for (int j = 0; j < 4; ++j) {
            __builtin_amdgcn_global_load_lds(
                (const __attribute__((address_space(1))) unsigned int*)
                    (Wt + (size_t)(col0 + j * 32 + srow) * K + k0 + scol),
                (__attribute__((address_space(3))) unsigned int*)
                    (&Bs[(j * 32 + wave * 8) * 64]),
                16, 0, 0);
        }
        // ---- A tile (128x64), 4 int4 chunks per thread, guarded on M ----
        #pragma unroll
        for (int i = 0; i < 4; ++i) {
            int c = t + 256 * i;
            int r = c >> 3, col = (c & 7) * 8;
            int gr = row0 + r;
            int4 v = make_int4(0, 0, 0, 0);
            if (gr < M)
                v = *reinterpret_cast<const int4*>(A + (size_t)gr * K + k0 + col);
            *reinterpret_cast<int4*>(&As[r][col]) = v;
        }
        __syncthreads();

        #pragma unroll
        for (int kk = 0; kk < 2; ++kk) {
            bf16x8 af[4], bfr[4];
            #pragma unroll
            for (int mi = 0; mi < 4; ++mi)
                af[mi] = *reinterpret_cast<const bf16x8*>(
                    &As[wm * 64 + mi * 16 + l16][kk * 32 + quad * 8]);
            #pragma unroll
            for (int ni = 0; ni < 4; ++ni)
                bfr[ni] = *reinterpret_cast<const bf16x8*>(
                    &Bs[(wn * 64 + ni * 16 + l16) * 64 + kk * 32 + quad * 8]);
            #pragma unroll
            for (int mi = 0; mi < 4; ++mi)
                #pragma unroll
                for (int ni = 0; ni < 4; ++ni)
                    acc[mi][ni] = __builtin_amdgcn_mfma_f32_16x16x32_bf16(
                        af[mi], bfr[ni], acc[mi][ni], 0, 0, 0);
        }
        __syncthreads();
    }

    // epilogue: D mapping col=lane&15, row=quad*4+i  [m89/m91]
    #pragma unroll
    for (int mi = 0; mi < 4; ++mi) {
        #pragma unroll
        for (int ni = 0; ni < 4; ++ni) {
            int ccol = col0 + wn * 64 + ni * 16 + l16;
            float bv = HAS_BIAS ? b2f(bias[ccol]) : 0.0f;
            #pragma unroll
            for (int i = 0; i < 4; ++i) {
                int r = row0 + wm * 64 + mi * 16 + quad * 4 + i;
                if (r < M) {
                    float v = acc[mi][ni][i] + bv;
                    if (LEAKY) v = (v >= 0.0f) ? v : 0.01f * v;
                    C[(size_t)r * N + ccol] = f2b(v);
                }
            }
        }
    }
}

// ---------- CSR gather over fused layer buffer P[*,768] ----------
// cols 0-255: rel0 h, 256-511: rel1 h, 512-767: root(+bias).
// One wave per node; FOUR quarter-waves process interleaved edges (4x MLP):
// quarter q = lane>>4, l16 = lane&15 covers ch l16*16..+16 via 2 int4 (32B/lane).
__global__ __launch_bounds__(256) void gather_kernel(
    const int* __restrict__ row_ptr, const int* __restrict__ packed,
    const float* __restrict__ inv,
    const unsigned short* __restrict__ P,     // [*,768] bf16
    unsigned short* __restrict__ outp,        // [*,256] bf16
    int NN)
{
    int i    = blockIdx.x * 4 + (threadIdx.x >> 6);
    int lane = threadIdx.x & 63;
    int q    = lane >> 4;
    int l16  = lane & 15;
    if (i >= NN) return;
    float w0 = inv[i], w1 = inv[NN + i];
    float a[16] = {};
    if (q == 0) {
        const int4* rp = (const int4*)(P + (size_t)i * 768 + 512 + l16 * 16);
        union { int4 v; unsigned short s[8]; } r0u, r1u;
        r0u.v = rp[0]; r1u.v = rp[1];
        #pragma unroll
        for (int j = 0; j < 8; ++j) { a[j] = b2f(r0u.s[j]); a[8 + j] = b2f(r1u.s[j]); }
    }
    int e1 = row_ptr[i + 1];
    for (int e = row_ptr[i] + q; e < e1; e += 4) {
        int p = packed[e];
        int s = p & 0xFFFFFF;
        if (s >= NN) s = NN - 1;
        int r = (p >> 24) & 1;
        float w = r ? w1 : w0;
        const int4* hp = (const int4*)(P + (size_t)s * 768 + r * 256 + l16 * 16);
        union { int4 v; unsigned short s8[8]; } h0, h1;
        h0.v = hp[0]; h1.v = hp[1];
        #pragma unroll
        for (int j = 0; j < 8; ++j) {
            a[j]     += w * b2f(h0.s8[j]);
            a[8 + j] += w * b2f(h1.s8[j]);
        }
    }
    // merge quarters: lanes l += l+32, then l += l+16
    #pragma unroll
    for (int j = 0; j < 16; ++j) {
        a[j] += __shfl_down(a[j], 32);
        a[j] += __shfl_down(a[j], 16);
    }
    if (q == 0) {
        union { int4 v; unsigned short s[8]; } o0, o1;
        #pragma unroll
        for (int j = 0; j < 8; ++j) { o0.s[j] = f2b(a[j]); o1.s[j] = f2b(a[8 + j]); }
        int4* op = (int4*)(outp + (size_t)i * 256 + l16 * 16);
        op[0] = o0.v;
        op[1] = o1.v;
    }
}

// ---------- head: softmax(h@outW + outb) over 2 classes; flag-aware store ----------
__global__ __launch_bounds__(256) void head_kernel(
    const unsigned short* __restrict__ h,
    const unsigned short* __restrict__ outW,   // [256,2] bf16 (converted)
    const unsigned short* __restrict__ outb,   // [2] bf16 (converted)
    void* __restrict__ out, int M, const int* __restrict__ flags)
{
    int row  = blockIdx.x * 4 + (threadIdx.x >> 6);
    int lane = threadIdx.x & 63;
    if (row >= M) return;
    ushort4 hv = *reinterpret_cast<const ushort4*>(h + (size_t)row * 256 + lane * 4);
    union { int4 v; unsigned short s[8]; } wu;
    wu.v = *reinterpret_cast<const int4*>(outW + lane * 8);
    float hf[4] = { b2f(hv.x), b2f(hv.y), b2f(hv.z), b2f(hv.w) };
    float s0 = 0.0f, s1 = 0.0f;
    #pragma unroll
    for (int i = 0; i < 4; ++i) {
        s0 += hf[i] * b2f(wu.s[2 * i]);
        s1 += hf[i] * b2f(wu.s[2 * i + 1]);
    }
    #pragma unroll
    for (int off2 = 32; off2 >= 1; off2 >>= 1) {
        s0 += __shfl_down(s0, off2);
        s1 += __shfl_down(s1, off2);
    }
    if (lane == 0) {
        s0 += b2f(outb[0]); s1 += b2f(outb[1]);
        float m  = fmaxf(s0, s1);
        float e0 = expf(s0 - m), e1 = expf(s1 - m);
        float is = 1.0f / (e0 + e1);
        if (flags[0]) {
            ((float*)out)[(size_t)row * 2 + 0] = e0 * is;
            ((float*)out)[(size_t)row * 2 + 1] = e1 * is;
        } else {
            ((unsigned short*)out)[(size_t)row * 2 + 0] = f2b(e0 * is);
            ((unsigned short*)out)[(size_t)row * 2 + 1] = f2b(e1 * is);
        }
    }
}

__global__ void diag_kernel(unsigned short* __restrict__ out, int n, float v) {
    int i = blockIdx.x * 256 + threadIdx.x;
    if (i < n) out[i] = f2b(v);
}

template<bool LEAKY, bool HAS_BIAS>
static void launch_gemm(const unsigned short* A, const unsigned short* Wt,
                        const unsigned short* bias, unsigned short* C,
                        int M, int N, int K, hipStream_t s) {
    int MP = (M + 127) & ~127;
    dim3 grid(N / 128, MP / 128);
    gemm_kernel<LEAKY, HAS_BIAS><<<grid, 256, 0, s>>>(A, Wt, bias, C, M, N, K);
}

extern "C" void kernel_launch(void* const* d_in, const int* in_sizes, int n_in,
                              void* d_out, int out_size, void* d_ws, size_t ws_size,
                              hipStream_t stream) {
    const int IN = 768, HID = 256;
    const int NN = in_sizes[0] / IN;        // 50000
    const int E  = in_sizes[3];             // 800000
    const int MP = (NN + 127) & ~127;       // 50048
    const int NB = (NN + 1023) / 1024;
    (void)n_in;

    const void* x    = d_in[0];
    const void* eidx = d_in[1];
    const void* etyp = d_in[3];
    const void* fc1W = d_in[4];
    const void* fc1b = d_in[5];
    const void* r1w  = d_in[6];
    const void* r1r  = d_in[7];
    const void* r1b  = d_in[8];
    const void* r2w  = d_in[9];
    const void* r2r  = d_in[10];
    const void* r2b  = d_in[11];
    const void* fc2W = d_in[12];
    const void* fc2b = d_in[13];
    const void* outW = d_in[14];
    const void* outb = d_in[15];

    // ---- workspace carve (~162 MB total; 187 MB proven available) ----
    char* ws = (char*)d_ws;
    size_t off = 0;
    auto carve = [&](size_t bytes) {
        char* p = ws + off; off += (bytes + 255) & ~(size_t)255; return p;
    };
    int*   flags = (int*)carve(64);
    unsigned short* fc1t  = (unsigned short*)carve((size_t)IN * IN * 2);
    unsigned short* Wcat1 = (unsigned short*)carve((size_t)IN * IN * 2);
    unsigned short* Wcat2 = (unsigned short*)carve((size_t)IN * HID * 2);
    unsigned short* fc2t  = (unsigned short*)carve((size_t)HID * HID * 2);
    unsigned short* fc1bc = (unsigned short*)carve((size_t)IN * 2);
    unsigned short* bcat1 = (unsigned short*)carve((size_t)IN * 2);
    unsigned short* bcat2 = (unsigned short*)carve((size_t)IN * 2);
    unsigned short* fc2bc = (unsigned short*)carve((size_t)HID * 2);
    unsigned short* outWc = (unsigned short*)carve((size_t)HID * 2 * 2);
    unsigned short* outbc = (unsigned short*)carve(2 * 2);
    int*   icnt    = (int*)carve((size_t)2 * NN * 4);
    float* inv     = (float*)carve((size_t)2 * NN * 4);
    int*   deg     = (int*)carve((size_t)NN * 4);
    int*   row_ptr = (int*)carve((size_t)(NN + 1) * 4);
    int*   pos     = (int*)carve((size_t)NN * 4);
    int*   bsum    = (int*)carve(256 * 4);
    int*   packed  = (int*)carve((size_t)E * 4);
    unsigned short* RA = (unsigned short*)carve((size_t)MP * IN * 2);  // 76.9 MB
    unsigned short* RB = (unsigned short*)carve((size_t)MP * IN * 2);  // 76.9 MB

    auto tg = [](int n) { return (n + 255) / 256; };

    if (ws_size < off) {
        float v = fminf((float)(ws_size >> 20), 300.0f) / 1000.0f;
        diag_kernel<<<tg(out_size), 256, 0, stream>>>((unsigned short*)d_out, out_size, v);
        return;
    }

    // ---- dtype detection ----
    detect_kernel<<<1, 256, 0, stream>>>(x, eidx, flags);

    // ---- weights: transpose+convert to [N,K] bf16; fused per layer ----
    convt_kernel<<<tg(IN * IN), 256, 0, stream>>>(fc1W, 0, fc1t, IN, IN, flags);
    convt_kernel<<<tg(IN * HID), 256, 0, stream>>>(r1w, 0, Wcat1, IN, HID, flags);
    convt_kernel<<<tg(IN * HID), 256, 0, stream>>>(r1w, (size_t)IN * HID, Wcat1 + (size_t)256 * IN, IN, HID, flags);
    convt_kernel<<<tg(IN * HID), 256, 0, stream>>>(r1r, 0, Wcat1 + (size_t)512 * IN, IN, HID, flags);
    convt_kernel<<<tg(HID * HID), 256, 0, stream>>>(r2w, 0, Wcat2, HID, HID, flags);
    convt_kernel<<<tg(HID * HID), 256, 0, stream>>>(r2w, (size_t)HID * HID, Wcat2 + (size_t)256 * HID, HID, HID, flags);
    convt_kernel<<<tg(HID * HID), 256, 0, stream>>>(r2r, 0, Wcat2 + (size_t)512 * HID, HID, HID, flags);
    convt_kernel<<<tg(HID * HID), 256, 0, stream>>>(fc2W, 0, fc2t, HID, HID, flags);
    zero_us_kernel<<<tg(512), 256, 0, stream>>>(bcat1, 512);
    zero_us_kernel<<<tg(512), 256, 0, stream>>>(bcat2, 512);
    convb_kernel<<<tg(IN), 256, 0, stream>>>(fc1b, fc1bc, IN, flags);
    convb_kernel<<<1, 256, 0, stream>>>(r1b, bcat1 + 512, HID, flags);
    convb_kernel<<<1, 256, 0, stream>>>(r2b, bcat2 + 512, HID, flags);
    convb_kernel<<<1, 256, 0, stream>>>(fc2b, fc2bc, HID, flags);
    convb_kernel<<<tg(HID * 2), 256, 0, stream>>>(outW, outWc, HID * 2, flags);
    convb_kernel<<<1, 256, 0, stream>>>(outb, outbc, 2, flags);

    // ---- CSR build ----
    zero_kernel<<<tg(2 * NN), 256, 0, stream>>>(icnt, 2 * NN);
    count_kernel<<<tg(E), 256, 0, stream>>>(eidx, etyp, icnt, E, NN, flags);
    inv_deg_kernel<<<tg(NN), 256, 0, stream>>>(icnt, inv, deg, NN);
    blocksum_kernel<<<NB, 256, 0, stream>>>(deg, bsum, NN);
    scan_bsum_kernel<<<1, 64, 0, stream>>>(bsum, NB);
    scan_phase3<<<NB, 256, 0, stream>>>(deg, bsum, row_ptr, pos, NN);
    fill_kernel<<<tg(E), 256, 0, stream>>>(eidx, etyp, pos, packed, E, NN, flags);

    // ---- x -> bf16 (RA) ----
    convx_kernel<<<tg(NN * IN / 8), 256, 0, stream>>>(x, RA, NN * IN / 8, flags);

    // ---- fc1 + leakyrelu: XB(RA) -> H1(RB) ----
    launch_gemm<true, true>(RA, fc1t, fc1bc, RB, NN, IN, IN, stream);

    // ---- layer 1 (fused): H1(RB) @ Wcat1 -> P1(RA) ; gather -> ACC1(RB head) ----
    launch_gemm<false, true>(RB, Wcat1, bcat1, RA, NN, IN, IN, stream);
    gather_kernel<<<(NN + 3) / 4, 256, 0, stream>>>(row_ptr, packed, inv, RA, RB, NN);

    // ---- layer 2 (fused): ACC1(RB) @ Wcat2 -> P2(RA) ; gather -> ACC2(RB head) ----
    launch_gemm<false, true>(RB, Wcat2, bcat2, RA, NN, IN, HID, stream);
    gather_kernel<<<(NN + 3) / 4, 256, 0, stream>>>(row_ptr, packed, inv, RA, RB, NN);

    // ---- fc2 + leakyrelu: ACC2(RB) -> H4(RA head) ; softmax head ----
    launch_gemm<true, true>(RB, fc2t, fc2bc, RA, NN, HID, HID, stream);
    head_kernel<<<(NN + 3) / 4, 256, 0, stream>>>(RA, outWc, outbc, d_out, NN, flags);
}

// Round 10
// 842.022 us; speedup vs baseline: 1.0498x; 1.0498x over previous
//
#include <hip/hip_runtime.h>
#include <stdint.h>

// ---------- bf16 helpers (raw ushort representation, RNE) ----------
__device__ __forceinline__ float b2f(unsigned short s) {
    union { uint32_t u; float f; } v; v.u = ((uint32_t)s) << 16; return v.f;
}
__device__ __forceinline__ unsigned short f2b(float f) {
    union { float f; uint32_t u; } v; v.f = f;
    uint32_t r = v.u + 0x7FFFu + ((v.u >> 16) & 1u);
    return (unsigned short)(r >> 16);
}
__device__ __forceinline__ int ld_idx(const void* p, long long i, int i64) {
    return i64 ? (int)((const long long*)p)[i] : ((const int*)p)[i];
}

typedef __bf16 bf16x8 __attribute__((ext_vector_type(8)));
typedef float  f32x4  __attribute__((ext_vector_type(4)));

// ---------- dtype detection: flags[0]=floats-are-f32, flags[1]=ints-are-i64 ----------
__global__ void detect_kernel(const void* __restrict__ x, const void* __restrict__ eidx,
                              int* __restrict__ flags) {
    __shared__ int cntF, cntI;
    int t = threadIdx.x;
    if (t == 0) { cntF = 0; cntI = 0; }
    __syncthreads();
    const unsigned short* xs = (const unsigned short*)x;
    int lf = 0;
    for (int i = t; i < 4096; i += 256) {
        unsigned short v = xs[2 * i];
        int e = (v >> 7) & 0xFF;
        if (v == 0 || (e >= 100 && e <= 140)) lf++;
    }
    const int* ei = (const int*)eidx;
    int li = 0;
    for (int i = t; i < 2048; i += 256)
        if (ei[2 * i + 1] != 0) li++;
    atomicAdd(&cntF, lf);
    atomicAdd(&cntI, li);
    __syncthreads();
    if (t == 0) {
        flags[0] = (cntF < 3000) ? 1 : 0;
        flags[1] = (cntI < 64) ? 1 : 0;
    }
}

// ---------- transpose + convert: Wt[n*K+k] = bf16(W[src_off + k*N+n]) ----------
__global__ void convt_kernel(const void* __restrict__ W, size_t src_off,
                             unsigned short* __restrict__ Wt, int K, int N,
                             const int* __restrict__ flags) {
    int id = blockIdx.x * 256 + threadIdx.x;
    if (id < K * N) {
        int n = id / K, k = id - n * K;
        size_t s = src_off + (size_t)k * N + n;
        Wt[id] = flags[0] ? f2b(((const float*)W)[s]) : ((const unsigned short*)W)[s];
    }
}

__global__ void convb_kernel(const void* __restrict__ src, unsigned short* __restrict__ dst,
                             int n, const int* __restrict__ flags) {
    int i = blockIdx.x * 256 + threadIdx.x;
    if (i < n)
        dst[i] = flags[0] ? f2b(((const float*)src)[i]) : ((const unsigned short*)src)[i];
}

// ---------- x -> bf16 bulk convert (8 elems/thread) ----------
__global__ void convx_kernel(const void* __restrict__ src, unsigned short* __restrict__ dst,
                             int n8, const int* __restrict__ flags) {
    int i = blockIdx.x * 256 + threadIdx.x;
    if (i < n8) {
        if (flags[0]) {
            const float4* p = (const float4*)src + (size_t)i * 2;
            float4 a = p[0], b = p[1];
            union { int4 v; unsigned short s[8]; } u;
            u.s[0] = f2b(a.x); u.s[1] = f2b(a.y); u.s[2] = f2b(a.z); u.s[3] = f2b(a.w);
            u.s[4] = f2b(b.x); u.s[5] = f2b(b.y); u.s[6] = f2b(b.z); u.s[7] = f2b(b.w);
            ((int4*)dst)[i] = u.v;
        } else {
            ((int4*)dst)[i] = ((const int4*)src)[i];
        }
    }
}

__global__ void zero_kernel(int* __restrict__ p, int n) {
    int i = blockIdx.x * 256 + threadIdx.x;
    if (i < n) p[i] = 0;
}
__global__ void zero_us_kernel(unsigned short* __restrict__ p, int n) {
    int i = blockIdx.x * 256 + threadIdx.x;
    if (i < n) p[i] = 0;
}

// ---------- per-(relation,dst) edge counts (flag-aware, clamped) ----------
__global__ void count_kernel(const void* __restrict__ eidx, const void* __restrict__ etype,
                             int* __restrict__ cnt, int E, int NN,
                             const int* __restrict__ flags) {
    int e = blockIdx.x * 256 + threadIdx.x;
    if (e < E) {
        int i64 = flags[1];
        int d = ld_idx(eidx, (long long)E + e, i64);
        d = min(max(d, 0), NN - 1);
        int ty = ld_idx(etype, e, i64) & 1;
        atomicAdd(&cnt[ty * NN + d], 1);
    }
}

__global__ void inv_deg_kernel(const int* __restrict__ cnt, float* __restrict__ inv,
                               int* __restrict__ deg, int NN) {
    int i = blockIdx.x * 256 + threadIdx.x;
    if (i < NN) {
        int c0 = cnt[i], c1 = cnt[NN + i];
        inv[i]      = 1.0f / (float)max(c0, 1);
        inv[NN + i] = 1.0f / (float)max(c1, 1);
        deg[i] = c0 + c1;
    }
}

// ---------- 3-phase parallel scan (round-7-proven) ----------
__global__ void blocksum_kernel(const int* __restrict__ deg, int* __restrict__ bsum, int n) {
    __shared__ int red[256];
    int t = threadIdx.x, b = blockIdx.x;
    int base = b * 1024 + t * 4;
    int s = 0;
    #pragma unroll
    for (int j = 0; j < 4; ++j) {
        int idx = base + j;
        if (idx < n) s += deg[idx];
    }
    red[t] = s;
    __syncthreads();
    for (int off = 128; off > 0; off >>= 1) {
        if (t < off) red[t] += red[t + off];
        __syncthreads();
    }
    if (t == 0) bsum[b] = red[0];
}
__global__ void scan_bsum_kernel(int* __restrict__ bsum, int nb) {
    if (threadIdx.x == 0 && blockIdx.x == 0) {
        int acc = 0;
        for (int i = 0; i < nb; ++i) { int v = bsum[i]; bsum[i] = acc; acc += v; }
    }
}
__global__ void scan_phase3(const int* __restrict__ deg, const int* __restrict__ bsum,
                            int* __restrict__ row_ptr, int* __restrict__ pos, int n) {
    __shared__ int buf[256];
    int t = threadIdx.x, b = blockIdx.x;
    int base = b * 1024;
    int v[4]; int s = 0;
    #pragma unroll
    for (int j = 0; j < 4; ++j) {
        int idx = base + t * 4 + j;
        v[j] = (idx < n) ? deg[idx] : 0;
        s += v[j];
    }
    buf[t] = s;
    __syncthreads();
    for (int off = 1; off < 256; off <<= 1) {
        int xv = (t >= off) ? buf[t - off] : 0;
        __syncthreads();
        buf[t] += xv;
        __syncthreads();
    }
    int run = buf[t] - s + bsum[b];
    #pragma unroll
    for (int j = 0; j < 4; ++j) {
        int idx = base + t * 4 + j;
        if (idx < n) {
            run += v[j];
            row_ptr[idx + 1] = run;
            if (idx + 1 < n) pos[idx + 1] = run;
        }
    }
    if (b == 0 && t == 0) { row_ptr[0] = 0; pos[0] = 0; }
}

// ---------- CSR fill: packed[slot] = (rel<<24) | src ----------
__global__ void fill_kernel(const void* __restrict__ eidx, const void* __restrict__ etype,
                            int* __restrict__ pos, int* __restrict__ packed, int E, int NN,
                            const int* __restrict__ flags) {
    int e = blockIdx.x * 256 + threadIdx.x;
    if (e < E) {
        int i64 = flags[1];
        int s = ld_idx(eidx, e, i64);
        int d = ld_idx(eidx, (long long)E + e, i64);
        s = min(max(s, 0), NN - 1);
        d = min(max(d, 0), NN - 1);
        int ty = ld_idx(etype, e, i64) & 1;
        int slot = atomicAdd(&pos[d], 1);
        packed[slot] = (ty << 24) | s;
    }
}

// ---------- MFMA bf16 GEMM (m97 structure): C = act(A @ Wt^T + bias) ----------
// Tile 128x128, BK=64, 256 threads = 4 waves (2x2), each wave 64x64 via 4x4 of 16x16x32.
// BOTH A and B staged via global_load_lds (no staging VGPRs, no M-guard needed:
// A must have ceil128(M) readable rows -- all inputs are ws buffers carved at MP rows;
// garbage rows >= M only feed C rows >= M which the guarded epilogue never stores).
// grid: x = N/128 fastest (A row-stripe L2 reuse), y = MP/128.
template<bool LEAKY, bool HAS_BIAS>
__global__ __launch_bounds__(256) void gemm_kernel(
    const unsigned short* __restrict__ A,    // [MP,K] bf16 (MP = ceil128(M) valid rows)
    const unsigned short* __restrict__ Wt,   // [N,K] bf16
    const unsigned short* __restrict__ bias, // [N] bf16, or null
    unsigned short* __restrict__ C,          // [M,N] bf16
    int M, int N, int K)
{
    __shared__ __align__(16) unsigned short As[128 * 64];
    __shared__ __align__(16) unsigned short Bs[128 * 64];

    const int t    = threadIdx.x;
    const int lane = t & 63;
    const int wave = t >> 6;
    const int wm   = wave >> 1;
    const int wn   = wave & 1;
    const int l16  = lane & 15;
    const int quad = lane >> 4;
    const int col0 = blockIdx.x * 128;
    const int row0 = blockIdx.y * 128;
    // staging coords: wave w, issue j covers LDS rows j*32 + w*8 .. +8 (64 lanes x 16B)
    const int srow = wave * 8 + (lane >> 3);
    const int scol = (lane & 7) * 8;

    f32x4 acc[4][4] = {};

    for (int k0 = 0; k0 < K; k0 += 64) {
        #pragma unroll
        for (int j = 0; j < 4; ++j) {
            __builtin_amdgcn_global_load_lds(
                (const __attribute__((address_space(1))) unsigned int*)
                    (A + (size_t)(row0 + j * 32 + srow) * K + k0 + scol),
                (__attribute__((address_space(3))) unsigned int*)
                    (&As[(j * 32 + wave * 8) * 64]),
                16, 0, 0);
            __builtin_amdgcn_global_load_lds(
                (const __attribute__((address_space(1))) unsigned int*)
                    (Wt + (size_t)(col0 + j * 32 + srow) * K + k0 + scol),
                (__attribute__((address_space(3))) unsigned int*)
                    (&Bs[(j * 32 + wave * 8) * 64]),
                16, 0, 0);
        }
        __syncthreads();

        #pragma unroll
        for (int kk = 0; kk < 2; ++kk) {
            bf16x8 af[4], bfr[4];
            #pragma unroll
            for (int mi = 0; mi < 4; ++mi)
                af[mi] = *reinterpret_cast<const bf16x8*>(
                    &As[(wm * 64 + mi * 16 + l16) * 64 + kk * 32 + quad * 8]);
            #pragma unroll
            for (int ni = 0; ni < 4; ++ni)
                bfr[ni] = *reinterpret_cast<const bf16x8*>(
                    &Bs[(wn * 64 + ni * 16 + l16) * 64 + kk * 32 + quad * 8]);
            #pragma unroll
            for (int mi = 0; mi < 4; ++mi)
                #pragma unroll
                for (int ni = 0; ni < 4; ++ni)
                    acc[mi][ni] = __builtin_amdgcn_mfma_f32_16x16x32_bf16(
                        af[mi], bfr[ni], acc[mi][ni], 0, 0, 0);
        }
        __syncthreads();
    }

    // epilogue: D mapping col=lane&15, row=quad*4+i  [m89/m91]
    #pragma unroll
    for (int mi = 0; mi < 4; ++mi) {
        #pragma unroll
        for (int ni = 0; ni < 4; ++ni) {
            int ccol = col0 + wn * 64 + ni * 16 + l16;
            float bv = HAS_BIAS ? b2f(bias[ccol]) : 0.0f;
            #pragma unroll
            for (int i = 0; i < 4; ++i) {
                int r = row0 + wm * 64 + mi * 16 + quad * 4 + i;
                if (r < M) {
                    float v = acc[mi][ni][i] + bv;
                    if (LEAKY) v = (v >= 0.0f) ? v : 0.01f * v;
                    C[(size_t)r * N + ccol] = f2b(v);
                }
            }
        }
    }
}

// ---------- CSR gather over fused layer buffer P[*,768] (r9-proven quarter-wave) ----------
// cols 0-255: rel0 h, 256-511: rel1 h, 512-767: root(+bias).
__global__ __launch_bounds__(256) void gather_kernel(
    const int* __restrict__ row_ptr, const int* __restrict__ packed,
    const float* __restrict__ inv,
    const unsigned short* __restrict__ P,     // [*,768] bf16
    unsigned short* __restrict__ outp,        // [*,256] bf16
    int NN)
{
    int i    = blockIdx.x * 4 + (threadIdx.x >> 6);
    int lane = threadIdx.x & 63;
    int q    = lane >> 4;
    int l16  = lane & 15;
    if (i >= NN) return;
    float w0 = inv[i], w1 = inv[NN + i];
    float a[16] = {};
    if (q == 0) {
        const int4* rp = (const int4*)(P + (size_t)i * 768 + 512 + l16 * 16);
        union { int4 v; unsigned short s[8]; } r0u, r1u;
        r0u.v = rp[0]; r1u.v = rp[1];
        #pragma unroll
        for (int j = 0; j < 8; ++j) { a[j] = b2f(r0u.s[j]); a[8 + j] = b2f(r1u.s[j]); }
    }
    int e1 = row_ptr[i + 1];
    for (int e = row_ptr[i] + q; e < e1; e += 4) {
        int p = packed[e];
        int s = p & 0xFFFFFF;
        if (s >= NN) s = NN - 1;
        int r = (p >> 24) & 1;
        float w = r ? w1 : w0;
        const int4* hp = (const int4*)(P + (size_t)s * 768 + r * 256 + l16 * 16);
        union { int4 v; unsigned short s8[8]; } h0, h1;
        h0.v = hp[0]; h1.v = hp[1];
        #pragma unroll
        for (int j = 0; j < 8; ++j) {
            a[j]     += w * b2f(h0.s8[j]);
            a[8 + j] += w * b2f(h1.s8[j]);
        }
    }
    #pragma unroll
    for (int j = 0; j < 16; ++j) {
        a[j] += __shfl_down(a[j], 32);
        a[j] += __shfl_down(a[j], 16);
    }
    if (q == 0) {
        union { int4 v; unsigned short s[8]; } o0, o1;
        #pragma unroll
        for (int j = 0; j < 8; ++j) { o0.s[j] = f2b(a[j]); o1.s[j] = f2b(a[8 + j]); }
        int4* op = (int4*)(outp + (size_t)i * 256 + l16 * 16);
        op[0] = o0.v;
        op[1] = o1.v;
    }
}

// ---------- head: softmax(h@outW + outb) over 2 classes; flag-aware store ----------
__global__ __launch_bounds__(256) void head_kernel(
    const unsigned short* __restrict__ h,
    const unsigned short* __restrict__ outW,   // [256,2] bf16 (converted)
    const unsigned short* __restrict__ outb,   // [2] bf16 (converted)
    void* __restrict__ out, int M, const int* __restrict__ flags)
{
    int row  = blockIdx.x * 4 + (threadIdx.x >> 6);
    int lane = threadIdx.x & 63;
    if (row >= M) return;
    ushort4 hv = *reinterpret_cast<const ushort4*>(h + (size_t)row * 256 + lane * 4);
    union { int4 v; unsigned short s[8]; } wu;
    wu.v = *reinterpret_cast<const int4*>(outW + lane * 8);
    float hf[4] = { b2f(hv.x), b2f(hv.y), b2f(hv.z), b2f(hv.w) };
    float s0 = 0.0f, s1 = 0.0f;
    #pragma unroll
    for (int i = 0; i < 4; ++i) {
        s0 += hf[i] * b2f(wu.s[2 * i]);
        s1 += hf[i] * b2f(wu.s[2 * i + 1]);
    }
    #pragma unroll
    for (int off2 = 32; off2 >= 1; off2 >>= 1) {
        s0 += __shfl_down(s0, off2);
        s1 += __shfl_down(s1, off2);
    }
    if (lane == 0) {
        s0 += b2f(outb[0]); s1 += b2f(outb[1]);
        float m  = fmaxf(s0, s1);
        float e0 = expf(s0 - m), e1 = expf(s1 - m);
        float is = 1.0f / (e0 + e1);
        if (flags[0]) {
            ((float*)out)[(size_t)row * 2 + 0] = e0 * is;
            ((float*)out)[(size_t)row * 2 + 1] = e1 * is;
        } else {
            ((unsigned short*)out)[(size_t)row * 2 + 0] = f2b(e0 * is);
            ((unsigned short*)out)[(size_t)row * 2 + 1] = f2b(e1 * is);
        }
    }
}

__global__ void diag_kernel(unsigned short* __restrict__ out, int n, float v) {
    int i = blockIdx.x * 256 + threadIdx.x;
    if (i < n) out[i] = f2b(v);
}

template<bool LEAKY, bool HAS_BIAS>
static void launch_gemm(const unsigned short* A, const unsigned short* Wt,
                        const unsigned short* bias, unsigned short* C,
                        int M, int N, int K, hipStream_t s) {
    int MP = (M + 127) & ~127;
    dim3 grid(N / 128, MP / 128);
    gemm_kernel<LEAKY, HAS_BIAS><<<grid, 256, 0, s>>>(A, Wt, bias, C, M, N, K);
}

extern "C" void kernel_launch(void* const* d_in, const int* in_sizes, int n_in,
                              void* d_out, int out_size, void* d_ws, size_t ws_size,
                              hipStream_t stream) {
    const int IN = 768, HID = 256;
    const int NN = in_sizes[0] / IN;        // 50000
    const int E  = in_sizes[3];             // 800000
    const int MP = (NN + 127) & ~127;       // 50048
    const int NB = (NN + 1023) / 1024;
    (void)n_in;

    const void* x    = d_in[0];
    const void* eidx = d_in[1];
    const void* etyp = d_in[3];
    const void* fc1W = d_in[4];
    const void* fc1b = d_in[5];
    const void* r1w  = d_in[6];
    const void* r1r  = d_in[7];
    const void* r1b  = d_in[8];
    const void* r2w  = d_in[9];
    const void* r2r  = d_in[10];
    const void* r2b  = d_in[11];
    const void* fc2W = d_in[12];
    const void* fc2b = d_in[13];
    const void* outW = d_in[14];
    const void* outb = d_in[15];

    // ---- workspace carve (~162 MB total; 187 MB proven available) ----
    char* ws = (char*)d_ws;
    size_t off = 0;
    auto carve = [&](size_t bytes) {
        char* p = ws + off; off += (bytes + 255) & ~(size_t)255; return p;
    };
    int*   flags = (int*)carve(64);
    unsigned short* fc1t  = (unsigned short*)carve((size_t)IN * IN * 2);
    unsigned short* Wcat1 = (unsigned short*)carve((size_t)IN * IN * 2);
    unsigned short* Wcat2 = (unsigned short*)carve((size_t)IN * HID * 2);
    unsigned short* fc2t  = (unsigned short*)carve((size_t)HID * HID * 2);
    unsigned short* fc1bc = (unsigned short*)carve((size_t)IN * 2);
    unsigned short* bcat1 = (unsigned short*)carve((size_t)IN * 2);
    unsigned short* bcat2 = (unsigned short*)carve((size_t)IN * 2);
    unsigned short* fc2bc = (unsigned short*)carve((size_t)HID * 2);
    unsigned short* outWc = (unsigned short*)carve((size_t)HID * 2 * 2);
    unsigned short* outbc = (unsigned short*)carve(2 * 2);
    int*   icnt    = (int*)carve((size_t)2 * NN * 4);
    float* inv     = (float*)carve((size_t)2 * NN * 4);
    int*   deg     = (int*)carve((size_t)NN * 4);
    int*   row_ptr = (int*)carve((size_t)(NN + 1) * 4);
    int*   pos     = (int*)carve((size_t)NN * 4);
    int*   bsum    = (int*)carve(256 * 4);
    int*   packed  = (int*)carve((size_t)E * 4);
    unsigned short* RA = (unsigned short*)carve((size_t)MP * IN * 2);  // 76.9 MB
    unsigned short* RB = (unsigned short*)carve((size_t)MP * IN * 2);  // 76.9 MB

    auto tg = [](int n) { return (n + 255) / 256; };

    if (ws_size < off) {
        float v = fminf((float)(ws_size >> 20), 300.0f) / 1000.0f;
        diag_kernel<<<tg(out_size), 256, 0, stream>>>((unsigned short*)d_out, out_size, v);
        return;
    }

    // ---- dtype detection ----
    detect_kernel<<<1, 256, 0, stream>>>(x, eidx, flags);

    // ---- weights: transpose+convert to [N,K] bf16; fused per layer ----
    convt_kernel<<<tg(IN * IN), 256, 0, stream>>>(fc1W, 0, fc1t, IN, IN, flags);
    convt_kernel<<<tg(IN * HID), 256, 0, stream>>>(r1w, 0, Wcat1, IN, HID, flags);
    convt_kernel<<<tg(IN * HID), 256, 0, stream>>>(r1w, (size_t)IN * HID, Wcat1 + (size_t)256 * IN, IN, HID, flags);
    convt_kernel<<<tg(IN * HID), 256, 0, stream>>>(r1r, 0, Wcat1 + (size_t)512 * IN, IN, HID, flags);
    convt_kernel<<<tg(HID * HID), 256, 0, stream>>>(r2w, 0, Wcat2, HID, HID, flags);
    convt_kernel<<<tg(HID * HID), 256, 0, stream>>>(r2w, (size_t)HID * HID, Wcat2 + (size_t)256 * HID, HID, HID, flags);
    convt_kernel<<<tg(HID * HID), 256, 0, stream>>>(r2r, 0, Wcat2 + (size_t)512 * HID, HID, HID, flags);
    convt_kernel<<<tg(HID * HID), 256, 0, stream>>>(fc2W, 0, fc2t, HID, HID, flags);
    zero_us_kernel<<<tg(512), 256, 0, stream>>>(bcat1, 512);
    zero_us_kernel<<<tg(512), 256, 0, stream>>>(bcat2, 512);
    convb_kernel<<<tg(IN), 256, 0, stream>>>(fc1b, fc1bc, IN, flags);
    convb_kernel<<<1, 256, 0, stream>>>(r1b, bcat1 + 512, HID, flags);
    convb_kernel<<<1, 256, 0, stream>>>(r2b, bcat2 + 512, HID, flags);
    convb_kernel<<<1, 256, 0, stream>>>(fc2b, fc2bc, HID, flags);
    convb_kernel<<<tg(HID * 2), 256, 0, stream>>>(outW, outWc, HID * 2, flags);
    convb_kernel<<<1, 256, 0, stream>>>(outb, outbc, 2, flags);

    // ---- CSR build ----
    zero_kernel<<<tg(2 * NN), 256, 0, stream>>>(icnt, 2 * NN);
    count_kernel<<<tg(E), 256, 0, stream>>>(eidx, etyp, icnt, E, NN, flags);
    inv_deg_kernel<<<tg(NN), 256, 0, stream>>>(icnt, inv, deg, NN);
    blocksum_kernel<<<NB, 256, 0, stream>>>(deg, bsum, NN);
    scan_bsum_kernel<<<1, 64, 0, stream>>>(bsum, NB);
    scan_phase3<<<NB, 256, 0, stream>>>(deg, bsum, row_ptr, pos, NN);
    fill_kernel<<<tg(E), 256, 0, stream>>>(eidx, etyp, pos, packed, E, NN, flags);

    // ---- x -> bf16 (RA) ----
    convx_kernel<<<tg(NN * IN / 8), 256, 0, stream>>>(x, RA, NN * IN / 8, flags);

    // ---- fc1 + leakyrelu: XB(RA) -> H1(RB) ----
    launch_gemm<true, true>(RA, fc1t, fc1bc, RB, NN, IN, IN, stream);

    // ---- layer 1 (fused): H1(RB) @ Wcat1 -> P1(RA) ; gather -> ACC1(RB head) ----
    launch_gemm<false, true>(RB, Wcat1, bcat1, RA, NN, IN, IN, stream);
    gather_kernel<<<(NN + 3) / 4, 256, 0, stream>>>(row_ptr, packed, inv, RA, RB, NN);

    // ---- layer 2 (fused): ACC1(RB) @ Wcat2 -> P2(RA) ; gather -> ACC2(RB head) ----
    launch_gemm<false, true>(RB, Wcat2, bcat2, RA, NN, IN, HID, stream);
    gather_kernel<<<(NN + 3) / 4, 256, 0, stream>>>(row_ptr, packed, inv, RA, RB, NN);

    // ---- fc2 + leakyrelu: ACC2(RB) -> H4(RA head) ; softmax head ----
    launch_gemm<true, true>(RB, fc2t, fc2bc, RA, NN, HID, HID, stream);
    head_kernel<<<(NN + 3) / 4, 256, 0, stream>>>(RA, outWc, outbc, d_out, NN, flags);
}